// Round 2
// baseline (1540.306 us; speedup 1.0000x reference)
//
#include <hip/hip_runtime.h>
#include <hip/hip_bf16.h>

#define NS 132  // LDS row stride (bf16 elems); 264B/row -> 2-dword bank shift, hits 8-cyc b128 floor

typedef __attribute__((ext_vector_type(8))) short short8;
typedef __attribute__((ext_vector_type(4))) float f32x4;

#define MFMA __builtin_amdgcn_mfma_f32_16x16x32_bf16

__device__ __forceinline__ float bf2f(unsigned short u){
  union { unsigned int i; float f; } v; v.i = ((unsigned int)u) << 16; return v.f;
}
__device__ __forceinline__ unsigned short f2bf(float f){
  unsigned int u = __float_as_uint(f);
  u += 0x7FFF + ((u >> 16) & 1);   // RNE
  return (unsigned short)(u >> 16);
}

struct Acc { f32x4 t[2][4]; };

__device__ __forceinline__ void accZero(Acc& o){
#pragma unroll
  for (int i=0;i<2;i++)
#pragma unroll
    for (int c=0;c<4;c++)
      o.t[i][c] = (f32x4){0.f,0.f,0.f,0.f};
}

// ---- weight pre-split + pack into per-lane fragment streaming order ----
// packed idx p (per weight, 16384): p = gtile*2048 + k*512 + lane*8 + j
//   -> logical (g = gtile*16 + (lane&15), f = (lane>>4)*8 + k*32 + j), value w_src[f][g]
// hi half at dst[w*16384 + p], lo half at dst[98304 + w*16384 + p]
__global__ void split_pack_weights_k(const float* __restrict__ w0, const float* __restrict__ w1,
                                     const float* __restrict__ w2, const float* __restrict__ w3,
                                     const float* __restrict__ w4, const float* __restrict__ w5,
                                     unsigned short* __restrict__ dst)
{
  int i = blockIdx.x*256 + threadIdx.x;        // 0..98303
  int w = i >> 14;
  int p = i & 16383;
  int gtile = p >> 11;
  int k     = (p >> 9) & 3;
  int lane8 = (p >> 3) & 63;
  int j     = p & 7;
  int g = gtile*16 + (lane8 & 15);
  int f = (lane8 >> 4)*8 + k*32 + j;
  const float* src = (w==0)?w0:(w==1)?w1:(w==2)?w2:(w==3)?w3:(w==4)?w4:w5;
  float v = src[f*128 + g];
  unsigned short hi = f2bf(v);
  unsigned short lo = f2bf(v - bf2f(hi));
  dst[i] = hi;
  dst[98304 + i] = lo;
}

// C = A(pair) * W(pair,global packed)^T : 6 MFMA per (k,c)
__device__ __forceinline__ void mm_pairA_gW(const unsigned short* Ah, const unsigned short* Al,
                                            const unsigned short* wgh, const unsigned short* wgl,
                                            int TR0, int TC0, int lane, Acc& o){
  const int ml = lane & 15, quad = lane >> 4;
  const unsigned short* pah = Ah + (TR0*16 + ml)*NS + quad*8;
  const unsigned short* pal = Al + (TR0*16 + ml)*NS + quad*8;
  const short8* bh = (const short8*)wgh;
  const short8* bl = (const short8*)wgl;
#pragma unroll
  for (int k=0;k<4;k++){
    short8 a0h = *(const short8*)(pah + k*32);
    short8 a1h = *(const short8*)(pah + 16*NS + k*32);
    short8 a0l = *(const short8*)(pal + k*32);
    short8 a1l = *(const short8*)(pal + 16*NS + k*32);
#pragma unroll
    for (int c=0;c<4;c++){
      short8 vh = bh[(TC0+c)*256 + k*64 + lane];
      short8 vl = bl[(TC0+c)*256 + k*64 + lane];
      o.t[0][c] = MFMA(a0h, vh, o.t[0][c], 0,0,0);
      o.t[0][c] = MFMA(a0h, vl, o.t[0][c], 0,0,0);
      o.t[0][c] = MFMA(a0l, vh, o.t[0][c], 0,0,0);
      o.t[1][c] = MFMA(a1h, vh, o.t[1][c], 0,0,0);
      o.t[1][c] = MFMA(a1h, vl, o.t[1][c], 0,0,0);
      o.t[1][c] = MFMA(a1l, vh, o.t[1][c], 0,0,0);
    }
  }
}

// C = A(single) * W(pair,global packed)^T : 4 MFMA per (k,c)
__device__ __forceinline__ void mm_singleA_gW(const unsigned short* A,
                                              const unsigned short* wgh, const unsigned short* wgl,
                                              int TR0, int TC0, int lane, Acc& o){
  const int ml = lane & 15, quad = lane >> 4;
  const unsigned short* pa = A + (TR0*16 + ml)*NS + quad*8;
  const short8* bh = (const short8*)wgh;
  const short8* bl = (const short8*)wgl;
#pragma unroll
  for (int k=0;k<4;k++){
    short8 a0 = *(const short8*)(pa + k*32);
    short8 a1 = *(const short8*)(pa + 16*NS + k*32);
#pragma unroll
    for (int c=0;c<4;c++){
      short8 vh = bh[(TC0+c)*256 + k*64 + lane];
      short8 vl = bl[(TC0+c)*256 + k*64 + lane];
      o.t[0][c] = MFMA(a0, vh, o.t[0][c], 0,0,0);
      o.t[0][c] = MFMA(a0, vl, o.t[0][c], 0,0,0);
      o.t[1][c] = MFMA(a1, vh, o.t[1][c], 0,0,0);
      o.t[1][c] = MFMA(a1, vl, o.t[1][c], 0,0,0);
    }
  }
}

// scores = Q(single) * K(pair)^T : 4 MFMA per (k,c)
__device__ __forceinline__ void mm_QK(const unsigned short* Q,
                                      const unsigned short* Kh, const unsigned short* Kl,
                                      int TR0, int TC0, int lane, Acc& o){
  const int ml = lane & 15, quad = lane >> 4;
  const unsigned short* pa  = Q  + (TR0*16 + ml)*NS + quad*8;
  const unsigned short* pbh = Kh + (TC0*16 + ml)*NS + quad*8;
  const unsigned short* pbl = Kl + (TC0*16 + ml)*NS + quad*8;
#pragma unroll
  for (int k=0;k<4;k++){
    short8 a0 = *(const short8*)(pa + k*32);
    short8 a1 = *(const short8*)(pa + 16*NS + k*32);
#pragma unroll
    for (int c=0;c<4;c++){
      short8 vh = *(const short8*)(pbh + c*16*NS + k*32);
      short8 vl = *(const short8*)(pbl + c*16*NS + k*32);
      o.t[0][c] = MFMA(a0, vh, o.t[0][c], 0,0,0);
      o.t[0][c] = MFMA(a0, vl, o.t[0][c], 0,0,0);
      o.t[1][c] = MFMA(a1, vh, o.t[1][c], 0,0,0);
      o.t[1][c] = MFMA(a1, vl, o.t[1][c], 0,0,0);
    }
  }
}

// attn = P(single) * VT(single)^T : 2 MFMA per (k,c)
__device__ __forceinline__ void mm_PV(const unsigned short* P, const unsigned short* VT,
                                      int TR0, int TC0, int lane, Acc& o){
  const int ml = lane & 15, quad = lane >> 4;
  const unsigned short* pa = P  + (TR0*16 + ml)*NS + quad*8;
  const unsigned short* pb = VT + (TC0*16 + ml)*NS + quad*8;
#pragma unroll
  for (int k=0;k<4;k++){
    short8 a0 = *(const short8*)(pa + k*32);
    short8 a1 = *(const short8*)(pa + 16*NS + k*32);
#pragma unroll
    for (int c=0;c<4;c++){
      short8 b = *(const short8*)(pb + c*16*NS + k*32);
      o.t[0][c] = MFMA(a0, b, o.t[0][c], 0,0,0);
      o.t[1][c] = MFMA(a1, b, o.t[1][c], 0,0,0);
    }
  }
}

__global__ __launch_bounds__(512, 2)
void fused_temporal_attn(const float* __restrict__ x, const float* __restrict__ te,
                         const unsigned short* __restrict__ wT,
                         const float* __restrict__ bq, const float* __restrict__ bk,
                         const float* __restrict__ bv, const float* __restrict__ bo,
                         const float* __restrict__ b1, const float* __restrict__ b2,
                         float* __restrict__ out)
{
  extern __shared__ char smem[];
  unsigned short* B0 = (unsigned short*)smem;          // Xh / Kh / attn / uh
  unsigned short* B1 = B0 + 128*NS;                    // Xl / Kl / ul
  unsigned short* B2 = B1 + 128*NS;                    // VT / H
  unsigned short* B3 = B2 + 128*NS;                    // Q / P
  float* SC = (float*)smem;                            // fp32 scores (over B0,B1)
  float* O1 = (float*)(smem + (size_t)2*128*NS*2);     // fp32 out1 / h2 (over B2,B3)

  const int tid  = threadIdx.x;
  const int lane = tid & 63;
  const int wave = tid >> 6;
  const int ml   = lane & 15;
  const int quad = lane >> 4;
  const int TR0  = 2*(wave & 3);
  const int TC0  = 4*(wave >> 2);

  const int bidx = blockIdx.x;
  const int n = bidx & 255;
  const int b = bidx >> 8;
  const long base = (long)b*(128L*256L*128L) + (long)n*128L;   // x[b,0,n,0]; t-stride 32768

  const unsigned short* WgH[6]; const unsigned short* WgL[6];
#pragma unroll
  for (int w=0;w<6;w++){ WgH[w] = wT + w*16384; WgL[w] = wT + 98304 + w*16384; }

  // ---- S1: X = x + te (fp32) -> hi/lo pair in B0,B1
  {
    const int r = tid >> 5, c = tid & 31;
    const float4* xp = (const float4*)(x + base);
    const float4* tp = (const float4*)(te + base);
#pragma unroll
    for (int p=0;p<8;p++){
      int t = p*16 + r;
      float4 a = xp[t*8192 + c];
      float4 e = tp[t*8192 + c];
      float v0=a.x+e.x, v1=a.y+e.y, v2=a.z+e.z, v3=a.w+e.w;
      ushort4 uh, ul;
      uh.x=f2bf(v0); ul.x=f2bf(v0-bf2f(uh.x));
      uh.y=f2bf(v1); ul.y=f2bf(v1-bf2f(uh.y));
      uh.z=f2bf(v2); ul.z=f2bf(v2-bf2f(uh.z));
      uh.w=f2bf(v3); ul.w=f2bf(v3-bf2f(uh.w));
      *(ushort4*)(B0 + t*NS + c*4) = uh;
      *(ushort4*)(B1 + t*NS + c*4) = ul;
    }
  }

  Acc acc;

  auto writeSingle = [&](unsigned short* dst, const float* bias, bool relu){
#pragma unroll
    for (int i=0;i<2;i++){
      int rowb = (TR0+i)*16 + quad*4;
#pragma unroll
      for (int c=0;c<4;c++){
        int col = (TC0+c)*16 + ml;
        float bb = bias ? bias[col] : 0.f;
#pragma unroll
        for (int r=0;r<4;r++){
          float v = acc.t[i][c][r] + bb;
          if (relu) v = fmaxf(v, 0.f);
          dst[(rowb+r)*NS + col] = f2bf(v);
        }
      }
    }
  };

  auto writePair = [&](unsigned short* dh, unsigned short* dl, const float* bias){
#pragma unroll
    for (int i=0;i<2;i++){
      int rowb = (TR0+i)*16 + quad*4;
#pragma unroll
      for (int c=0;c<4;c++){
        int col = (TC0+c)*16 + ml;
        float bb = bias[col];
#pragma unroll
        for (int r=0;r<4;r++){
          float v = acc.t[i][c][r] + bb;
          unsigned short hi = f2bf(v);
          dh[(rowb+r)*NS + col] = hi;
          dl[(rowb+r)*NS + col] = f2bf(v - bf2f(hi));
        }
      }
    }
  };

  auto writeF32 = [&](float* dst, const float* bias){
#pragma unroll
    for (int i=0;i<2;i++){
      int rowb = (TR0+i)*16 + quad*4;
#pragma unroll
      for (int c=0;c<4;c++){
        int col = (TC0+c)*16 + ml;
        float bb = bias ? bias[col] : 0.f;
#pragma unroll
        for (int r=0;r<4;r++)
          dst[(rowb+r)*NS + col] = acc.t[i][c][r] + bb;
      }
    }
  };

  auto writeVT = [&](unsigned short* dst, const float* bias){   // dst[f][s] = C[s][f]+b[f]
#pragma unroll
    for (int i=0;i<2;i++){
      int rowb = (TR0+i)*16 + quad*4;
#pragma unroll
      for (int c=0;c<4;c++){
        int col = (TC0+c)*16 + ml;
        float bb = bias[col];
        ushort4 u;
        u.x = f2bf(acc.t[i][c][0] + bb);
        u.y = f2bf(acc.t[i][c][1] + bb);
        u.z = f2bf(acc.t[i][c][2] + bb);
        u.w = f2bf(acc.t[i][c][3] + bb);
        *(ushort4*)(dst + col*NS + rowb) = u;
      }
    }
  };

  __syncthreads();

  // ---- S2: V = X*wv^T + bv -> VT (single) in B2
  accZero(acc); mm_pairA_gW(B0, B1, WgH[2], WgL[2], TR0, TC0, lane, acc);
  writeVT(B2, bv);
  __syncthreads();

  // ---- S3: Q = X*wq^T + bq -> single in B3
  accZero(acc); mm_pairA_gW(B0, B1, WgH[0], WgL[0], TR0, TC0, lane, acc);
  writeSingle(B3, bq, false);
  __syncthreads();

  // ---- S4: K = X*wk^T + bk -> pair OVER X (B0,B1); X dead (residual re-read later)
  accZero(acc); mm_pairA_gW(B0, B1, WgH[1], WgL[1], TR0, TC0, lane, acc);
  __syncthreads();                       // all X reads complete
  writePair(B0, B1, bk);
  __syncthreads();

  // ---- S5: scores = Q*K^T / 4, causal mask -> fp32 SC over B0,B1 (K dead after mm)
  accZero(acc); mm_QK(B3, B0, B1, TR0, TC0, lane, acc);
  __syncthreads();                       // all K reads complete
  {
#pragma unroll
    for (int i=0;i<2;i++){
      int rowb = (TR0+i)*16 + quad*4;
#pragma unroll
      for (int c=0;c<4;c++){
        int col = (TC0+c)*16 + ml;
#pragma unroll
        for (int r=0;r<4;r++){
          int row = rowb + r;
          SC[row*NS + col] = (col <= row) ? acc.t[i][c][r]*0.25f : -32767.0f;
        }
      }
    }
  }
  __syncthreads();

  // ---- S6: softmax(SC) -> P (single) in B3 (Q dead)
  {
    const int row = tid >> 2, q = tid & 3;
    const float4* srcp = (const float4*)(SC + row*NS + q*32);
    float4 e[8];
    float mx = -3.0e38f;
#pragma unroll
    for (int i2=0;i2<8;i2++){
      float4 v = srcp[i2];
      e[i2] = v;
      mx = fmaxf(mx, fmaxf(fmaxf(v.x,v.y), fmaxf(v.z,v.w)));
    }
    mx = fmaxf(mx, __shfl_xor(mx, 1, 64));
    mx = fmaxf(mx, __shfl_xor(mx, 2, 64));
    float s = 0.f;
#pragma unroll
    for (int i2=0;i2<8;i2++){
      e[i2].x = __expf(e[i2].x - mx);
      e[i2].y = __expf(e[i2].y - mx);
      e[i2].z = __expf(e[i2].z - mx);
      e[i2].w = __expf(e[i2].w - mx);
      s += e[i2].x + e[i2].y + e[i2].z + e[i2].w;
    }
    s += __shfl_xor(s, 1, 64);
    s += __shfl_xor(s, 2, 64);
    float rinv = 1.f / s;
    unsigned short* dstp = B3 + row*NS + q*32;
#pragma unroll
    for (int i2=0;i2<8;i2++){
      ushort4 u;
      u.x = f2bf(e[i2].x * rinv);
      u.y = f2bf(e[i2].y * rinv);
      u.z = f2bf(e[i2].z * rinv);
      u.w = f2bf(e[i2].w * rinv);
      *(ushort4*)(dstp + i2*4) = u;
    }
  }
  __syncthreads();

  // ---- S7: attn = P * V -> single in B0 (SC dead)
  accZero(acc); mm_PV(B3, B2, TR0, TC0, lane, acc);
  writeSingle(B0, nullptr, false);
  __syncthreads();

  // ---- S8: out1 = attn*wo^T + bo -> fp32 O1 (over B2,B3; VT,P dead);
  //          then u = LN(out1 + x + te) -> pair in B0,B1 (attn dead)
  accZero(acc); mm_singleA_gW(B0, WgH[3], WgL[3], TR0, TC0, lane, acc);
  writeF32(O1, bo);
  __syncthreads();
  {
    const int row = tid >> 2, q = tid & 3;
    const float4* o1 = (const float4*)(O1 + row*NS);
    const float4* gx = (const float4*)(x  + base + (long)row*32768);
    const float4* gt = (const float4*)(te + base + (long)row*32768);
    float vals[32];
    float s=0.f, s2=0.f;
#pragma unroll
    for (int i2=0;i2<8;i2++){
      float4 a = o1[q*8 + i2];
      float4 xv = gx[q*8 + i2];
      float4 tv = gt[q*8 + i2];
      float w0=a.x+xv.x+tv.x, w1=a.y+xv.y+tv.y, w2=a.z+xv.z+tv.z, w3=a.w+xv.w+tv.w;
      vals[i2*4+0]=w0; vals[i2*4+1]=w1; vals[i2*4+2]=w2; vals[i2*4+3]=w3;
      s += w0+w1+w2+w3;
      s2 += w0*w0+w1*w1+w2*w2+w3*w3;
    }
    s  += __shfl_xor(s, 1, 64);  s  += __shfl_xor(s, 2, 64);
    s2 += __shfl_xor(s2, 1, 64); s2 += __shfl_xor(s2, 2, 64);
    float mean = s * 0.0078125f;
    float var  = s2 * 0.0078125f - mean*mean;
    float rstd = rsqrtf(var + 1e-5f);
    unsigned short* dh = B0 + row*NS + q*32;
    unsigned short* dl = B1 + row*NS + q*32;
#pragma unroll
    for (int i2=0;i2<8;i2++){
      ushort4 uh, ul;
      float v0=(vals[i2*4+0]-mean)*rstd, v1=(vals[i2*4+1]-mean)*rstd;
      float v2=(vals[i2*4+2]-mean)*rstd, v3=(vals[i2*4+3]-mean)*rstd;
      uh.x=f2bf(v0); ul.x=f2bf(v0-bf2f(uh.x));
      uh.y=f2bf(v1); ul.y=f2bf(v1-bf2f(uh.y));
      uh.z=f2bf(v2); ul.z=f2bf(v2-bf2f(uh.z));
      uh.w=f2bf(v3); ul.w=f2bf(v3-bf2f(uh.w));
      *(ushort4*)(dh + i2*4) = uh;
      *(ushort4*)(dl + i2*4) = ul;
    }
  }
  __syncthreads();

  // ---- S9: H = relu(u*w1^T + b1) -> single in B2 (O1 dead)
  accZero(acc); mm_pairA_gW(B0, B1, WgH[4], WgL[4], TR0, TC0, lane, acc);
  writeSingle(B2, b1, true);
  __syncthreads();

  // ---- S10: h2 = H*w2^T + b2 -> fp32 O1 (over B2,B3; H dead after mm)
  accZero(acc); mm_singleA_gW(B2, WgH[5], WgL[5], TR0, TC0, lane, acc);
  __syncthreads();                      // all H reads complete
  writeF32(O1, b2);
  __syncthreads();

  // ---- S11: out = LN(h2 + u) -> global fp32
  {
    const int row = tid >> 2, q = tid & 3;
    const float4* h2 = (const float4*)(O1 + row*NS);
    const short8* ph = (const short8*)(B0 + row*NS + q*32);
    const short8* pl = (const short8*)(B1 + row*NS + q*32);
    float vals[32];
    float s=0.f, s2=0.f;
#pragma unroll
    for (int i2=0;i2<4;i2++){
      short8 vh = ph[i2];
      short8 vl = pl[i2];
#pragma unroll
      for (int j=0;j<8;j++){
        float u = bf2f((unsigned short)vh[j]) + bf2f((unsigned short)vl[j]);
        int idx = i2*8 + j;
        float4 hv = h2[q*8 + (idx>>2)];
        float hcomp = (idx&3)==0 ? hv.x : (idx&3)==1 ? hv.y : (idx&3)==2 ? hv.z : hv.w;
        float v = u + hcomp;
        vals[idx] = v; s += v; s2 += v*v;
      }
    }
    s  += __shfl_xor(s, 1, 64);  s  += __shfl_xor(s, 2, 64);
    s2 += __shfl_xor(s2, 1, 64); s2 += __shfl_xor(s2, 2, 64);
    float mean = s * 0.0078125f;
    float var  = s2 * 0.0078125f - mean*mean;
    float rstd = rsqrtf(var + 1e-5f);
    float4* gout = (float4*)(out + base + (long)row*32768);
#pragma unroll
    for (int i2=0;i2<8;i2++){
      float4 o4;
      o4.x = (vals[i2*4+0]-mean)*rstd;
      o4.y = (vals[i2*4+1]-mean)*rstd;
      o4.z = (vals[i2*4+2]-mean)*rstd;
      o4.w = (vals[i2*4+3]-mean)*rstd;
      gout[q*8 + i2] = o4;
    }
  }
}

extern "C" void kernel_launch(void* const* d_in, const int* in_sizes, int n_in,
                              void* d_out, int out_size, void* d_ws, size_t ws_size,
                              hipStream_t stream)
{
  const float* x  = (const float*)d_in[0];
  const float* te = (const float*)d_in[1];
  const float* wq = (const float*)d_in[2];
  const float* bq = (const float*)d_in[3];
  const float* wk = (const float*)d_in[4];
  const float* bk = (const float*)d_in[5];
  const float* wv = (const float*)d_in[6];
  const float* bv = (const float*)d_in[7];
  const float* wo = (const float*)d_in[8];
  const float* bo = (const float*)d_in[9];
  const float* w1 = (const float*)d_in[10];
  const float* b1 = (const float*)d_in[11];
  const float* w2 = (const float*)d_in[12];
  const float* b2 = (const float*)d_in[13];
  float* out = (float*)d_out;
  unsigned short* wT = (unsigned short*)d_ws;   // needs 2*6*128*128*2 = 393216 B

  split_pack_weights_k<<<384, 256, 0, stream>>>(wq, wk, wv, wo, w1, w2, wT);

  const int lds_bytes = 4*128*NS*2;  // 135168
  hipFuncSetAttribute(reinterpret_cast<const void*>(fused_temporal_attn),
                      hipFuncAttributeMaxDynamicSharedMemorySize, lds_bytes);
  fused_temporal_attn<<<4096, 512, lds_bytes, stream>>>(x, te, wT, bq, bk, bv, bo, b1, b2, out);
}